// Round 1
// baseline (304.341 us; speedup 1.0000x reference)
//
#include <hip/hip_runtime.h>
#include <hip/hip_bf16.h>
#include <math.h>

typedef __hip_bfloat16 bf16;
typedef __attribute__((ext_vector_type(8))) short short8;
typedef __attribute__((ext_vector_type(4))) float f32x4;

#define GLD16(gp, lp)                                                          \
    __builtin_amdgcn_global_load_lds(                                          \
        (const __attribute__((address_space(1))) unsigned int*)(gp),           \
        (__attribute__((address_space(3))) unsigned int*)(lp), 16, 0, 0)

// ---------------- conversion kernels ----------------

// x fp32 -> bf16, 8 elems/thread, exact cover: 8,388,608 / (256*8) = 4096 blocks
__global__ __launch_bounds__(256) void cvt_x(const float* __restrict__ in,
                                             bf16* __restrict__ out) {
    long base = ((long)blockIdx.x * 256 + threadIdx.x) * 8;
    const float4* p = (const float4*)(in + base);
    float4 a = p[0], b = p[1];
    union { bf16 h[8]; short8 v; } o;
    o.h[0] = __float2bfloat16(a.x); o.h[1] = __float2bfloat16(a.y);
    o.h[2] = __float2bfloat16(a.z); o.h[3] = __float2bfloat16(a.w);
    o.h[4] = __float2bfloat16(b.x); o.h[5] = __float2bfloat16(b.y);
    o.h[6] = __float2bfloat16(b.z); o.h[7] = __float2bfloat16(b.w);
    *(short8*)(out + base) = o.v;
}

// W [1024(k)][1024(n)] fp32 -> WT [1024(n)][1024(k)] bf16  (3 weights via z)
__global__ __launch_bounds__(256) void cvt_w_t(const float* __restrict__ Wq,
                                               const float* __restrict__ Wk,
                                               const float* __restrict__ Wv,
                                               bf16* __restrict__ WT) {
    const float* W = blockIdx.z == 0 ? Wq : (blockIdx.z == 1 ? Wk : Wv);
    bf16* T = WT + (long)blockIdx.z * 1024 * 1024;
    __shared__ float t[32][33];
    int n0 = blockIdx.x * 32, k0 = blockIdx.y * 32;
    int tx = threadIdx.x, ty = threadIdx.y;  // block (32,8)
    #pragma unroll
    for (int i = 0; i < 4; ++i)
        t[ty * 4 + i][tx] = W[(long)(k0 + ty * 4 + i) * 1024 + n0 + tx];
    __syncthreads();
    #pragma unroll
    for (int i = 0; i < 4; ++i)
        T[(long)(n0 + ty * 4 + i) * 1024 + k0 + tx] =
            __float2bfloat16(t[tx][ty * 4 + i]);
}

// ---------------- GEMM: C = A * B^T  (both A,B row-major [rows][K]) ----------
// MODE 0: fp32 store with alpha    MODE 1: bf16 store    MODE 2: bf16 V^T store
// TRI: blockIdx.x decodes lower-triangle tile (tm,tn), tn<=tm
// PVK: Keff = (tm+1)*128 (causal K truncation for P@V)
template <int MODE, bool TRI, bool PVK>
__global__ __launch_bounds__(256) void gemm_bt(const bf16* __restrict__ A,
                                               const bf16* __restrict__ B,
                                               void* __restrict__ C, int K,
                                               int lda, int ldb, int ldc,
                                               float alpha, long az, long bz,
                                               long cz) {
    int tm, tn;
    if (TRI) {
        int t = blockIdx.x;
        int i = (int)((sqrtf(8.f * t + 1.f) - 1.f) * 0.5f);
        while ((i + 1) * (i + 2) / 2 <= t) ++i;
        while (i * (i + 1) / 2 > t) --i;
        tm = i; tn = t - i * (i + 1) / 2;
    } else {
        tn = blockIdx.x; tm = blockIdx.y;
    }
    const int Keff = PVK ? (tm + 1) * 128 : K;

    A += (long)blockIdx.z * az;
    B += (long)blockIdx.z * bz;

    const int m0 = tm * 128, n0 = tn * 128;
    __shared__ bf16 As[128 * 32];
    __shared__ bf16 Bs[128 * 32];

    const int tid = threadIdx.x;
    const int wave = tid >> 6, lane = tid & 63;
    const int wr = wave >> 1, wc = wave & 1;     // 2x2 waves, 64x64 each
    const int lrow = lane & 15, kg = lane >> 4;  // fragment addressing

    f32x4 acc[4][4];
    #pragma unroll
    for (int i = 0; i < 4; ++i)
        #pragma unroll
        for (int j = 0; j < 4; ++j) acc[i][j] = (f32x4){0.f, 0.f, 0.f, 0.f};

    // staging: thread t covers LDS bytes [t*16, t*16+16) of each 4KB half
    const int srow = tid >> 2;            // 0..63
    const int scol = (tid & 3) << 3;      // 0,8,16,24 (bf16 elems)
    const bf16* ap = A + (long)(m0 + srow) * lda + scol;
    const bf16* bp = B + (long)(n0 + srow) * ldb + scol;
    char* asb = (char*)As + tid * 16;
    char* bsb = (char*)Bs + tid * 16;

    for (int k0 = 0; k0 < Keff; k0 += 32) {
        GLD16(ap + k0, asb);
        GLD16(ap + 64L * lda + k0, asb + 4096);
        GLD16(bp + k0, bsb);
        GLD16(bp + 64L * ldb + k0, bsb + 4096);
        __syncthreads();
        short8 af[4], bfr[4];
        #pragma unroll
        for (int mi = 0; mi < 4; ++mi)
            af[mi] = *(const short8*)(As + (wr * 64 + mi * 16 + lrow) * 32 + kg * 8);
        #pragma unroll
        for (int ni = 0; ni < 4; ++ni)
            bfr[ni] = *(const short8*)(Bs + (wc * 64 + ni * 16 + lrow) * 32 + kg * 8);
        #pragma unroll
        for (int mi = 0; mi < 4; ++mi)
            #pragma unroll
            for (int ni = 0; ni < 4; ++ni)
                acc[mi][ni] = __builtin_amdgcn_mfma_f32_16x16x32_bf16(
                    af[mi], bfr[ni], acc[mi][ni], 0, 0, 0);
        __syncthreads();
    }

    // C/D layout: col = lane&15, row = (lane>>4)*4 + j   [m89-verified]
    const int rb = wr * 64 + (lane >> 4) * 4;
    const int cb = wc * 64 + (lane & 15);
    if (MODE == 0) {
        float* Cf = (float*)C + (long)blockIdx.z * cz;
        #pragma unroll
        for (int mi = 0; mi < 4; ++mi)
            #pragma unroll
            for (int ni = 0; ni < 4; ++ni)
                #pragma unroll
                for (int j = 0; j < 4; ++j)
                    Cf[(long)(m0 + rb + mi * 16 + j) * ldc + (n0 + cb + ni * 16)] =
                        acc[mi][ni][j] * alpha;
    } else if (MODE == 1) {
        bf16* Cb = (bf16*)C;
        #pragma unroll
        for (int mi = 0; mi < 4; ++mi)
            #pragma unroll
            for (int ni = 0; ni < 4; ++ni)
                #pragma unroll
                for (int j = 0; j < 4; ++j)
                    Cb[(long)(m0 + rb + mi * 16 + j) * ldc + (n0 + cb + ni * 16)] =
                        __float2bfloat16(acc[mi][ni][j]);
    } else {
        // V^T: [4 batches][1024 cols][2048 seq], 4 consecutive rows -> 8B store
        bf16* T = (bf16*)C;
        #pragma unroll
        for (int mi = 0; mi < 4; ++mi)
            #pragma unroll
            for (int ni = 0; ni < 4; ++ni) {
                int gm = m0 + rb + mi * 16;
                int col = n0 + cb + ni * 16;
                int b = gm >> 11, mm = gm & 2047;
                union { bf16 h[4]; ushort4 v; } o;
                #pragma unroll
                for (int j = 0; j < 4; ++j)
                    o.h[j] = __float2bfloat16(acc[mi][ni][j]);
                *(ushort4*)(T + (long)b * 2097152 + (long)col * 2048 + mm) = o.v;
            }
    }
}

// ---------------- causal row softmax, fp32 scores -> bf16 P in-place ---------
__global__ __launch_bounds__(256) void softmax_pass(float* __restrict__ scores) {
    const int S = 2048;
    long row = blockIdx.x;  // b*S + q
    int q = (int)(row & (S - 1));
    float* sr = scores + row * (long)S;
    int tid = threadIdx.x, lane = tid & 63, wave = tid >> 6;
    int base = tid * 8;
    float4 v0 = *(const float4*)(sr + base);
    float4 v1 = *(const float4*)(sr + base + 4);
    float v[8] = {v0.x, v0.y, v0.z, v0.w, v1.x, v1.y, v1.z, v1.w};
    float mx = -1e30f;
    #pragma unroll
    for (int j = 0; j < 8; ++j) {
        if (base + j > q) v[j] = -1e30f;
        mx = fmaxf(mx, v[j]);
    }
    #pragma unroll
    for (int o = 32; o > 0; o >>= 1) mx = fmaxf(mx, __shfl_xor(mx, o));
    __shared__ float red[8];
    if (lane == 0) red[wave] = mx;
    __syncthreads();
    mx = fmaxf(fmaxf(red[0], red[1]), fmaxf(red[2], red[3]));
    float s = 0.f;
    #pragma unroll
    for (int j = 0; j < 8; ++j) {
        float e = (base + j <= q) ? __expf(v[j] - mx) : 0.f;
        v[j] = e;
        s += e;
    }
    #pragma unroll
    for (int o = 32; o > 0; o >>= 1) s += __shfl_xor(s, o);
    if (lane == 0) red[4 + wave] = s;
    __syncthreads();
    s = red[4] + red[5] + red[6] + red[7];
    float inv = 1.f / s;
    bf16* pr = (bf16*)sr;  // in-place: P row pitch = 4096 bf16 = 2048 f32
    union { bf16 h[8]; short8 w; } o;
    #pragma unroll
    for (int j = 0; j < 8; ++j) o.h[j] = __float2bfloat16(v[j] * inv);
    *(short8*)(pr + base) = o.w;
}

// ---------------- launch ----------------
extern "C" void kernel_launch(void* const* d_in, const int* in_sizes, int n_in,
                              void* d_out, int out_size, void* d_ws,
                              size_t ws_size, hipStream_t stream) {
    const float* x = (const float*)d_in[0];
    const float* Wq = (const float*)d_in[1];
    const float* Wk = (const float*)d_in[2];
    const float* Wv = (const float*)d_in[3];
    float* out = (float*)d_out;

    // workspace layout (bytes)
    char* ws = (char*)d_ws;
    bf16* xb = (bf16*)ws;                     // 8192x1024 bf16     16.78 MB
    bf16* wt = (bf16*)(ws + 16777216);        // 3x 1024x1024 bf16   6.29 MB
    bf16* Qb = (bf16*)(ws + 23068672);        // 8192x1024 bf16
    bf16* Kb = (bf16*)(ws + 39845888);        // 8192x1024 bf16
    bf16* VT = (bf16*)(ws + 56623104);        // 4x 1024x2048 bf16
    float* SC = (float*)(ws + 73400320);      // 4x 2048x2048 fp32  67.11 MB
    if (ws_size < 140509184) return;          // visible failure, no OOB

    cvt_x<<<4096, 256, 0, stream>>>(x, xb);
    cvt_w_t<<<dim3(32, 32, 3), dim3(32, 8), 0, stream>>>(Wq, Wk, Wv, wt);
    // Q, K, V projections (M=8192, N=1024, K=1024)
    gemm_bt<1, false, false><<<dim3(8, 64), 256, 0, stream>>>(
        xb, wt, Qb, 1024, 1024, 1024, 1024, 1.f, 0, 0, 0);
    gemm_bt<1, false, false><<<dim3(8, 64), 256, 0, stream>>>(
        xb, wt + 1048576, Kb, 1024, 1024, 1024, 1024, 1.f, 0, 0, 0);
    gemm_bt<2, false, false><<<dim3(8, 64), 256, 0, stream>>>(
        xb, wt + 2097152, VT, 1024, 1024, 1024, 0, 1.f, 0, 0, 0);
    // scores = Q K^T / 32, lower-triangle tiles only (16 tiles -> 136 pairs)
    gemm_bt<0, true, false><<<dim3(136, 1, 4), 256, 0, stream>>>(
        Qb, Kb, SC, 1024, 1024, 1024, 2048, 0.03125f, 2097152, 2097152, 4194304);
    softmax_pass<<<8192, 256, 0, stream>>>(SC);
    // O = P V  (P bf16 aliased over SC, lda=4096; causal Keff per row-tile)
    gemm_bt<0, false, true><<<dim3(8, 16, 4), 256, 0, stream>>>(
        (bf16*)SC, VT, out, 2048, 4096, 2048, 1024, 1.f, 8388608, 2097152,
        2097152);
}

// Round 2
// 259.941 us; speedup vs baseline: 1.1708x; 1.1708x over previous
//
#include <hip/hip_runtime.h>
#include <hip/hip_bf16.h>
#include <math.h>

typedef __hip_bfloat16 bf16;
typedef __attribute__((ext_vector_type(8))) short short8;
typedef __attribute__((ext_vector_type(4))) float f32x4;

#define GLD16(gp, lp)                                                          \
    __builtin_amdgcn_global_load_lds(                                          \
        (const __attribute__((address_space(1))) unsigned int*)(gp),           \
        (__attribute__((address_space(3))) unsigned int*)(lp), 16, 0, 0)

// ---------------- conversion kernels ----------------

// x fp32 -> bf16, 8 elems/thread: 8,388,608 / (256*8) = 4096 blocks exact
__global__ __launch_bounds__(256) void cvt_x(const float* __restrict__ in,
                                             bf16* __restrict__ out) {
    long base = ((long)blockIdx.x * 256 + threadIdx.x) * 8;
    const float4* p = (const float4*)(in + base);
    float4 a = p[0], b = p[1];
    union { bf16 h[8]; short8 v; } o;
    o.h[0] = __float2bfloat16(a.x); o.h[1] = __float2bfloat16(a.y);
    o.h[2] = __float2bfloat16(a.z); o.h[3] = __float2bfloat16(a.w);
    o.h[4] = __float2bfloat16(b.x); o.h[5] = __float2bfloat16(b.y);
    o.h[6] = __float2bfloat16(b.z); o.h[7] = __float2bfloat16(b.w);
    *(short8*)(out + base) = o.v;
}

// W [1024(k)][1024(n)] fp32 -> WT [1024(n)][1024(k)] bf16  (3 weights via z)
// stacked: WT is [3072][1024] row-major -> single fused-QKV B operand
__global__ __launch_bounds__(256) void cvt_w_t(const float* __restrict__ Wq,
                                               const float* __restrict__ Wk,
                                               const float* __restrict__ Wv,
                                               bf16* __restrict__ WT) {
    const float* W = blockIdx.z == 0 ? Wq : (blockIdx.z == 1 ? Wk : Wv);
    bf16* T = WT + (long)blockIdx.z * 1024 * 1024;
    __shared__ float t[32][33];
    int n0 = blockIdx.x * 32, k0 = blockIdx.y * 32;
    int tx = threadIdx.x, ty = threadIdx.y;  // block (32,8)
    #pragma unroll
    for (int i = 0; i < 4; ++i)
        t[ty * 4 + i][tx] = W[(long)(k0 + ty * 4 + i) * 1024 + n0 + tx];
    __syncthreads();
    #pragma unroll
    for (int i = 0; i < 4; ++i)
        T[(long)(n0 + ty * 4 + i) * 1024 + k0 + tx] =
            __float2bfloat16(t[tx][ty * 4 + i]);
}

// ---------------- GEMM: C = A * B^T  (A,B row-major [rows][K]) ---------------
// MODE 0: fp32 store with alpha (C0)     MODE 1: fused QKV epilogue (C0/C1/C2)
// TRI: 1D grid 544 = 4 batches x 136 lower-tri tiles
// PVK: 1D grid 512, heavy-first tm decode; Keff = (tm+1)*128
// K-loop: double-buffered LDS, stage(t+1) issued before compute(t), ONE
// __syncthreads per step (its vmcnt/lgkm drain is the only wait).
template <int MODE, bool TRI, bool PVK>
__global__ __launch_bounds__(256) void gemm_bt(
    const bf16* __restrict__ A, const bf16* __restrict__ B,
    void* __restrict__ C0, void* __restrict__ C1, void* __restrict__ C2,
    int K, int lda, int ldb, int ldc, float alpha, long az, long bz, long cz) {
    int tm, tn, bi = 0;
    if (MODE == 1) {
        tn = blockIdx.x; tm = blockIdx.y;
    } else if (TRI) {
        int t = blockIdx.x % 136;
        bi = blockIdx.x / 136;
        int i = (int)((sqrtf(8.f * t + 1.f) - 1.f) * 0.5f);
        while ((i + 1) * (i + 2) / 2 <= t) ++i;
        while (i * (i + 1) / 2 > t) --i;
        tm = i; tn = t - i * (i + 1) / 2;
    } else {  // PV: heavy row-tiles first
        tm = 15 - (int)(blockIdx.x >> 5);
        int r = blockIdx.x & 31;
        tn = r & 7; bi = r >> 3;
    }
    const int Keff = PVK ? (tm + 1) * 128 : K;
    A += (long)bi * az;
    B += (long)bi * bz;

    const int m0 = tm * 128, n0 = tn * 128;
    __shared__ bf16 As[2][128 * 32];
    __shared__ bf16 Bs[2][128 * 32];

    const int tid = threadIdx.x;
    const int wave = tid >> 6, lane = tid & 63;
    const int wr = wave >> 1, wc = wave & 1;     // 2x2 waves, 64x64 each
    const int lrow = lane & 15, kg = lane >> 4;

    f32x4 acc[4][4];
    #pragma unroll
    for (int i = 0; i < 4; ++i)
        #pragma unroll
        for (int j = 0; j < 4; ++j) acc[i][j] = (f32x4){0.f, 0.f, 0.f, 0.f};

    // staging: thread t covers bytes [t*16, t*16+16) of each 4KB half-buffer
    const int srow = tid >> 2;        // 0..63
    const int scol = (tid & 3) << 3;  // bf16 elems
    const bf16* ap = A + (long)(m0 + srow) * lda + scol;
    const bf16* bp = B + (long)(n0 + srow) * ldb + scol;
    const int nk = Keff >> 5;

    {   // prologue: stage tile 0 into buf 0
        char* ad = (char*)(&As[0][0]) + tid * 16;
        char* bd = (char*)(&Bs[0][0]) + tid * 16;
        GLD16(ap, ad);
        GLD16(ap + 64L * lda, ad + 4096);
        GLD16(bp, bd);
        GLD16(bp + 64L * ldb, bd + 4096);
    }
    __syncthreads();

    for (int t = 0; t < nk; ++t) {
        const int cur = t & 1;
        if (t + 1 < nk) {  // issue next-tile loads BEFORE compute
            const int k0 = (t + 1) << 5;
            char* ad = (char*)(&As[cur ^ 1][0]) + tid * 16;
            char* bd = (char*)(&Bs[cur ^ 1][0]) + tid * 16;
            GLD16(ap + k0, ad);
            GLD16(ap + 64L * lda + k0, ad + 4096);
            GLD16(bp + k0, bd);
            GLD16(bp + 64L * ldb + k0, bd + 4096);
        }
        short8 af[4], bfr[4];
        #pragma unroll
        for (int mi = 0; mi < 4; ++mi)
            af[mi] = *(const short8*)(&As[cur][(wr * 64 + mi * 16 + lrow) * 32 + kg * 8]);
        #pragma unroll
        for (int ni = 0; ni < 4; ++ni)
            bfr[ni] = *(const short8*)(&Bs[cur][(wc * 64 + ni * 16 + lrow) * 32 + kg * 8]);
        #pragma unroll
        for (int mi = 0; mi < 4; ++mi)
            #pragma unroll
            for (int ni = 0; ni < 4; ++ni)
                acc[mi][ni] = __builtin_amdgcn_mfma_f32_16x16x32_bf16(
                    af[mi], bfr[ni], acc[mi][ni], 0, 0, 0);
        __syncthreads();  // drains stage (vmcnt) + reads (lgkm) in one wait
    }

    // C/D layout: col = lane&15, row = (lane>>4)*4 + j   [m89-verified]
    const int rb = wr * 64 + (lane >> 4) * 4;
    const int cb = wc * 64 + (lane & 15);
    if (MODE == 0) {
        float* Cf = (float*)C0 + (long)bi * cz;
        #pragma unroll
        for (int mi = 0; mi < 4; ++mi)
            #pragma unroll
            for (int ni = 0; ni < 4; ++ni)
                #pragma unroll
                for (int j = 0; j < 4; ++j)
                    Cf[(long)(m0 + rb + mi * 16 + j) * ldc + (n0 + cb + ni * 16)] =
                        acc[mi][ni][j] * alpha;
    } else {
        const int sel = n0 >> 10;     // 0=Q, 1=K, 2=V (uniform per block)
        const int nb = n0 & 1023;
        if (sel < 2) {
            bf16* Cb = sel ? (bf16*)C1 : (bf16*)C0;
            #pragma unroll
            for (int mi = 0; mi < 4; ++mi)
                #pragma unroll
                for (int ni = 0; ni < 4; ++ni)
                    #pragma unroll
                    for (int j = 0; j < 4; ++j)
                        Cb[(long)(m0 + rb + mi * 16 + j) * 1024 + (nb + cb + ni * 16)] =
                            __float2bfloat16(acc[mi][ni][j]);
        } else {
            // V^T: [4 batches][1024 cols][2048 seq]; 4 rows -> one 8B store
            bf16* T = (bf16*)C2;
            #pragma unroll
            for (int mi = 0; mi < 4; ++mi)
                #pragma unroll
                for (int ni = 0; ni < 4; ++ni) {
                    int gm = m0 + rb + mi * 16;
                    int col = nb + cb + ni * 16;
                    int b = gm >> 11, mm = gm & 2047;
                    union { bf16 h[4]; ushort4 v; } o;
                    #pragma unroll
                    for (int j = 0; j < 4; ++j)
                        o.h[j] = __float2bfloat16(acc[mi][ni][j]);
                    *(ushort4*)(T + (long)b * 2097152 + (long)col * 2048 + mm) = o.v;
                }
        }
    }
}

// ---------------- causal row softmax, fp32 scores -> bf16 P in-place ---------
__global__ __launch_bounds__(256) void softmax_pass(float* __restrict__ scores) {
    const int S = 2048;
    long row = blockIdx.x;  // b*S + q
    int q = (int)(row & (S - 1));
    float* sr = scores + row * (long)S;
    int tid = threadIdx.x, lane = tid & 63, wave = tid >> 6;
    int base = tid * 8;
    float4 v0 = *(const float4*)(sr + base);
    float4 v1 = *(const float4*)(sr + base + 4);
    float v[8] = {v0.x, v0.y, v0.z, v0.w, v1.x, v1.y, v1.z, v1.w};
    float mx = -1e30f;
    #pragma unroll
    for (int j = 0; j < 8; ++j) {
        if (base + j > q) v[j] = -1e30f;
        mx = fmaxf(mx, v[j]);
    }
    #pragma unroll
    for (int o = 32; o > 0; o >>= 1) mx = fmaxf(mx, __shfl_xor(mx, o));
    __shared__ float red[8];
    if (lane == 0) red[wave] = mx;
    __syncthreads();
    mx = fmaxf(fmaxf(red[0], red[1]), fmaxf(red[2], red[3]));
    float s = 0.f;
    #pragma unroll
    for (int j = 0; j < 8; ++j) {
        float e = (base + j <= q) ? __expf(v[j] - mx) : 0.f;
        v[j] = e;
        s += e;
    }
    #pragma unroll
    for (int o = 32; o > 0; o >>= 1) s += __shfl_xor(s, o);
    if (lane == 0) red[4 + wave] = s;
    __syncthreads();
    s = red[4] + red[5] + red[6] + red[7];
    float inv = 1.f / s;
    bf16* pr = (bf16*)sr;  // in-place: P row pitch = 4096 bf16 = 2048 f32
    union { bf16 h[8]; short8 w; } o;
    #pragma unroll
    for (int j = 0; j < 8; ++j) o.h[j] = __float2bfloat16(v[j] * inv);
    *(short8*)(pr + base) = o.w;
}

// ---------------- launch ----------------
extern "C" void kernel_launch(void* const* d_in, const int* in_sizes, int n_in,
                              void* d_out, int out_size, void* d_ws,
                              size_t ws_size, hipStream_t stream) {
    const float* x = (const float*)d_in[0];
    const float* Wq = (const float*)d_in[1];
    const float* Wk = (const float*)d_in[2];
    const float* Wv = (const float*)d_in[3];
    float* out = (float*)d_out;

    // workspace layout (bytes)
    char* ws = (char*)d_ws;
    bf16* xb = (bf16*)ws;                     // 8192x1024 bf16     16.78 MB
    bf16* wt = (bf16*)(ws + 16777216);        // 3072x1024 bf16      6.29 MB
    bf16* Qb = (bf16*)(ws + 23068672);        // 8192x1024 bf16
    bf16* Kb = (bf16*)(ws + 39845888);        // 8192x1024 bf16
    bf16* VT = (bf16*)(ws + 56623104);        // 4x 1024x2048 bf16
    float* SC = (float*)(ws + 73400320);      // 4x 2048x2048 fp32  67.11 MB
    if (ws_size < 140509184) return;          // visible failure, no OOB

    cvt_x<<<4096, 256, 0, stream>>>(x, xb);
    cvt_w_t<<<dim3(32, 32, 3), dim3(32, 8), 0, stream>>>(Wq, Wk, Wv, wt);
    // fused QKV projection: M=8192, N=3072, K=1024 -> 1536 blocks (6/CU)
    gemm_bt<1, false, false><<<dim3(24, 64), 256, 0, stream>>>(
        xb, wt, Qb, Kb, VT, 1024, 1024, 1024, 0, 1.f, 0, 0, 0);
    // scores = Q K^T / 32, lower-triangle tiles (4 x 136 = 544 blocks)
    gemm_bt<0, true, false><<<544, 256, 0, stream>>>(
        Qb, Kb, SC, nullptr, nullptr, 1024, 1024, 1024, 2048, 0.03125f,
        2097152, 2097152, 4194304);
    softmax_pass<<<8192, 256, 0, stream>>>(SC);
    // O = P V  (P bf16 aliased over SC, lda=4096; heavy-first causal Keff)
    gemm_bt<0, false, true><<<512, 256, 0, stream>>>(
        (bf16*)SC, VT, out, nullptr, nullptr, 2048, 4096, 2048, 1024, 1.f,
        8388608, 2097152, 2097152);
}

// Round 3
// 246.257 us; speedup vs baseline: 1.2359x; 1.0556x over previous
//
#include <hip/hip_runtime.h>
#include <hip/hip_bf16.h>
#include <math.h>

typedef __hip_bfloat16 bf16;
typedef __attribute__((ext_vector_type(8))) short short8;
typedef __attribute__((ext_vector_type(4))) float f32x4;

#define GLD16(gp, lp)                                                          \
    __builtin_amdgcn_global_load_lds(                                          \
        (const __attribute__((address_space(1))) unsigned int*)(gp),           \
        (__attribute__((address_space(3))) unsigned int*)(lp), 16, 0, 0)

// ---------------- conversion kernels ----------------

__global__ __launch_bounds__(256) void cvt_x(const float* __restrict__ in,
                                             bf16* __restrict__ out) {
    long base = ((long)blockIdx.x * 256 + threadIdx.x) * 8;
    const float4* p = (const float4*)(in + base);
    float4 a = p[0], b = p[1];
    union { bf16 h[8]; short8 v; } o;
    o.h[0] = __float2bfloat16(a.x); o.h[1] = __float2bfloat16(a.y);
    o.h[2] = __float2bfloat16(a.z); o.h[3] = __float2bfloat16(a.w);
    o.h[4] = __float2bfloat16(b.x); o.h[5] = __float2bfloat16(b.y);
    o.h[6] = __float2bfloat16(b.z); o.h[7] = __float2bfloat16(b.w);
    *(short8*)(out + base) = o.v;
}

// W [1024(k)][1024(n)] fp32 -> WT [1024(n)][1024(k)] bf16, stacked [3072][1024]
__global__ __launch_bounds__(256) void cvt_w_t(const float* __restrict__ Wq,
                                               const float* __restrict__ Wk,
                                               const float* __restrict__ Wv,
                                               bf16* __restrict__ WT) {
    const float* W = blockIdx.z == 0 ? Wq : (blockIdx.z == 1 ? Wk : Wv);
    bf16* T = WT + (long)blockIdx.z * 1024 * 1024;
    __shared__ float t[32][33];
    int n0 = blockIdx.x * 32, k0 = blockIdx.y * 32;
    int tx = threadIdx.x, ty = threadIdx.y;  // block (32,8)
    #pragma unroll
    for (int i = 0; i < 4; ++i)
        t[ty * 4 + i][tx] = W[(long)(k0 + ty * 4 + i) * 1024 + n0 + tx];
    __syncthreads();
    #pragma unroll
    for (int i = 0; i < 4; ++i)
        T[(long)(n0 + ty * 4 + i) * 1024 + k0 + tx] =
            __float2bfloat16(t[tx][ty * 4 + i]);
}

// ---------------- GEMM: C = A * B^T  (A,B row-major [rows][K]) ---------------
// MODE 0: scores epilogue -> E=exp(s/32) bf16 (causal-masked) + fp32 rowsum atomics
// MODE 1: fused QKV epilogue (Q->C0 bf16, K->C1 bf16, V->C2 transposed bf16)
// MODE 2: PV epilogue -> fp32 out scaled by 1/rowsum
// TRI: 1D grid = 4 batches x 136 lower-tri tiles    PVK: Keff=(tm+1)*128
//
// LDS swizzle (kills the 8-way ds_read_b128 conflict at 64B row stride):
// phys chunk p of row r holds logical 16B chunk ((r>>1)&3)^p. Source is
// pre-swizzled (global_load_lds dest must stay linear); reads XOR the same.
// Slot map (4r + ((r>>1)&3)^kg) mod 8 is bijective in r mod 8 -> 2-way = free.
template <int MODE, bool TRI, bool PVK>
__global__ __launch_bounds__(256) void gemm_bt(
    const bf16* __restrict__ A, const bf16* __restrict__ B,
    void* __restrict__ C0, void* __restrict__ C1, void* __restrict__ C2,
    float* __restrict__ RS, int K, int lda, int ldb, int ldc, float alpha,
    long az, long bz, long cz) {
    int tm, tn, bi = 0;
    if (MODE == 1) {
        tn = blockIdx.x; tm = blockIdx.y;
    } else if (TRI) {
        int t = blockIdx.x % 136;
        bi = blockIdx.x / 136;
        int i = (int)((sqrtf(8.f * t + 1.f) - 1.f) * 0.5f);
        while ((i + 1) * (i + 2) / 2 <= t) ++i;
        while (i * (i + 1) / 2 > t) --i;
        tm = i; tn = t - i * (i + 1) / 2;
    } else {  // PV: heavy row-tiles first
        tm = 15 - (int)(blockIdx.x >> 5);
        int r = blockIdx.x & 31;
        tn = r & 7; bi = r >> 3;
    }
    const int Keff = PVK ? (tm + 1) * 128 : K;
    A += (long)bi * az;
    B += (long)bi * bz;

    const int m0 = tm * 128, n0 = tn * 128;
    __shared__ bf16 As[2][128 * 32];
    __shared__ bf16 Bs[2][128 * 32];

    const int tid = threadIdx.x;
    const int wave = tid >> 6, lane = tid & 63;
    const int wr = wave >> 1, wc = wave & 1;     // 2x2 waves, 64x64 each
    const int lrow = lane & 15, kg = lane >> 4;

    f32x4 acc[4][4];
    #pragma unroll
    for (int i = 0; i < 4; ++i)
        #pragma unroll
        for (int j = 0; j < 4; ++j) acc[i][j] = (f32x4){0.f, 0.f, 0.f, 0.f};

    // staging: thread t fills phys chunk (t&3) of row (t>>2) [+64 for 2nd half]
    const int srow = tid >> 2;
    const int scol = ((((srow >> 1) & 3) ^ (tid & 3)) << 3);  // swizzled source
    const bf16* ap = A + (long)(m0 + srow) * lda + scol;
    const bf16* bp = B + (long)(n0 + srow) * ldb + scol;
    const int nk = Keff >> 5;

    {   // prologue: stage tile 0 into buf 0
        char* ad = (char*)(&As[0][0]) + tid * 16;
        char* bd = (char*)(&Bs[0][0]) + tid * 16;
        GLD16(ap, ad);
        GLD16(ap + 64L * lda, ad + 4096);
        GLD16(bp, bd);
        GLD16(bp + 64L * ldb, bd + 4096);
    }
    __syncthreads();

    for (int t = 0; t < nk; ++t) {
        const int cur = t & 1;
        if (t + 1 < nk) {  // issue next-tile loads BEFORE compute
            const int k0 = (t + 1) << 5;
            char* ad = (char*)(&As[cur ^ 1][0]) + tid * 16;
            char* bd = (char*)(&Bs[cur ^ 1][0]) + tid * 16;
            GLD16(ap + k0, ad);
            GLD16(ap + 64L * lda + k0, ad + 4096);
            GLD16(bp + k0, bd);
            GLD16(bp + 64L * ldb + k0, bd + 4096);
        }
        short8 af[4], bfr[4];
        #pragma unroll
        for (int mi = 0; mi < 4; ++mi) {
            const int ck = ((mi * 8 + (lrow >> 1)) & 3) ^ kg;  // swizzled read
            af[mi] = *(const short8*)(&As[cur][(wr * 64 + mi * 16 + lrow) * 32 + ck * 8]);
        }
        #pragma unroll
        for (int ni = 0; ni < 4; ++ni) {
            const int ck = ((ni * 8 + (lrow >> 1)) & 3) ^ kg;
            bfr[ni] = *(const short8*)(&Bs[cur][(wc * 64 + ni * 16 + lrow) * 32 + ck * 8]);
        }
        #pragma unroll
        for (int mi = 0; mi < 4; ++mi)
            #pragma unroll
            for (int ni = 0; ni < 4; ++ni)
                acc[mi][ni] = __builtin_amdgcn_mfma_f32_16x16x32_bf16(
                    af[mi], bfr[ni], acc[mi][ni], 0, 0, 0);
        __syncthreads();
    }

    // C/D layout: col = lane&15, row = (lane>>4)*4 + j   [m89-verified]
    const int rb = wr * 64 + (lane >> 4) * 4;
    const int cb = wc * 64 + (lane & 15);
    if (MODE == 0) {
        // E = exp(acc/32) masked causal, bf16; atomic fp32 row sums
        bf16* E = (bf16*)C0 + (long)bi * cz;
        float* rsb = RS + bi * 2048;
        #pragma unroll
        for (int mi = 0; mi < 4; ++mi)
            #pragma unroll
            for (int j = 0; j < 4; ++j) {
                const int gq = m0 + rb + mi * 16 + j;
                float rp = 0.f;
                #pragma unroll
                for (int ni = 0; ni < 4; ++ni) {
                    const int gk = n0 + cb + ni * 16;
                    float e = (gk <= gq) ? __expf(acc[mi][ni][j] * alpha) : 0.f;
                    E[(long)gq * 2048 + gk] = __float2bfloat16(e);
                    rp += e;
                }
                #pragma unroll
                for (int o = 1; o < 16; o <<= 1) rp += __shfl_xor(rp, o);
                if ((lane & 15) == 0) atomicAdd(rsb + gq, rp);
            }
    } else if (MODE == 2) {
        float* Cf = (float*)C0 + (long)bi * cz;
        const float* rsb = RS + bi * 2048;
        #pragma unroll
        for (int mi = 0; mi < 4; ++mi)
            #pragma unroll
            for (int j = 0; j < 4; ++j) {
                const int gq = m0 + rb + mi * 16 + j;
                const float inv = 1.f / rsb[gq];
                #pragma unroll
                for (int ni = 0; ni < 4; ++ni)
                    Cf[(long)gq * ldc + (n0 + cb + ni * 16)] =
                        acc[mi][ni][j] * inv;
            }
    } else {
        const int sel = n0 >> 10;  // 0=Q, 1=K, 2=V (uniform per block)
        const int nb = n0 & 1023;
        if (sel < 2) {
            bf16* Cb = sel ? (bf16*)C1 : (bf16*)C0;
            #pragma unroll
            for (int mi = 0; mi < 4; ++mi)
                #pragma unroll
                for (int ni = 0; ni < 4; ++ni)
                    #pragma unroll
                    for (int j = 0; j < 4; ++j)
                        Cb[(long)(m0 + rb + mi * 16 + j) * 1024 + (nb + cb + ni * 16)] =
                            __float2bfloat16(acc[mi][ni][j]);
        } else {
            // V^T: [4 batches][1024 cols][2048 seq]; 4 rows -> one 8B store
            bf16* T = (bf16*)C2;
            #pragma unroll
            for (int mi = 0; mi < 4; ++mi)
                #pragma unroll
                for (int ni = 0; ni < 4; ++ni) {
                    int gm = m0 + rb + mi * 16;
                    int col = nb + cb + ni * 16;
                    int b = gm >> 11, mm = gm & 2047;
                    union { bf16 h[4]; ushort4 v; } o;
                    #pragma unroll
                    for (int j = 0; j < 4; ++j)
                        o.h[j] = __float2bfloat16(acc[mi][ni][j]);
                    *(ushort4*)(T + (long)b * 2097152 + (long)col * 2048 + mm) = o.v;
                }
        }
    }
}

// ---------------- launch ----------------
extern "C" void kernel_launch(void* const* d_in, const int* in_sizes, int n_in,
                              void* d_out, int out_size, void* d_ws,
                              size_t ws_size, hipStream_t stream) {
    const float* x = (const float*)d_in[0];
    const float* Wq = (const float*)d_in[1];
    const float* Wk = (const float*)d_in[2];
    const float* Wv = (const float*)d_in[3];
    float* out = (float*)d_out;

    // workspace layout (bytes)
    char* ws = (char*)d_ws;
    bf16* xb = (bf16*)ws;                     // 8192x1024 bf16     16.78 MB
    bf16* wt = (bf16*)(ws + 16777216);        // 3072x1024 bf16      6.29 MB
    bf16* Qb = (bf16*)(ws + 23068672);        // 8192x1024 bf16
    bf16* Kb = (bf16*)(ws + 39845888);        // 8192x1024 bf16
    bf16* VT = (bf16*)(ws + 56623104);        // 4x 1024x2048 bf16
    bf16* E  = (bf16*)(ws + 73400320);        // 4x 2048x2048 bf16  33.55 MB
    float* rs = (float*)(ws + 106954752);     // 4x 2048 fp32       32 KB
    if (ws_size < 106987520) return;          // visible failure, no OOB

    cvt_x<<<4096, 256, 0, stream>>>(x, xb);
    cvt_w_t<<<dim3(32, 32, 3), dim3(32, 8), 0, stream>>>(Wq, Wk, Wv, wt);
    hipMemsetAsync(rs, 0, 4 * 2048 * sizeof(float), stream);
    // fused QKV projection: M=8192, N=3072, K=1024 -> 1536 blocks (6/CU)
    gemm_bt<1, false, false><<<dim3(24, 64), 256, 0, stream>>>(
        xb, wt, Qb, Kb, VT, nullptr, 1024, 1024, 1024, 0, 1.f, 0, 0, 0);
    // E = exp(Q K^T / 32) causal, + row sums (4 x 136 = 544 blocks)
    gemm_bt<0, true, false><<<544, 256, 0, stream>>>(
        Qb, Kb, E, nullptr, nullptr, rs, 1024, 1024, 1024, 2048, 0.03125f,
        2097152, 2097152, 4194304);
    // O = (E V) / rowsum  (heavy-first causal Keff)
    gemm_bt<2, false, true><<<512, 256, 0, stream>>>(
        E, VT, out, nullptr, nullptr, rs, 2048, 2048, 2048, 1024, 1.f,
        4194304, 2097152, 2097152);
}

// Round 6
// 243.497 us; speedup vs baseline: 1.2499x; 1.0113x over previous
//
#include <hip/hip_runtime.h>
#include <hip/hip_bf16.h>
#include <math.h>

typedef __hip_bfloat16 bf16;
typedef __attribute__((ext_vector_type(8))) short short8;
typedef __attribute__((ext_vector_type(4))) float f32x4;

#define GLD16(gp, lp)                                                          \
    __builtin_amdgcn_global_load_lds(                                          \
        (const __attribute__((address_space(1))) unsigned int*)(gp),           \
        (__attribute__((address_space(3))) unsigned int*)(lp), 16, 0, 0)

// ---------------- conversion kernels ----------------

__global__ __launch_bounds__(256) void cvt_x(const float* __restrict__ in,
                                             bf16* __restrict__ out) {
    long base = ((long)blockIdx.x * 256 + threadIdx.x) * 8;
    const float4* p = (const float4*)(in + base);
    float4 a = p[0], b = p[1];
    union { bf16 h[8]; short8 v; } o;
    o.h[0] = __float2bfloat16(a.x); o.h[1] = __float2bfloat16(a.y);
    o.h[2] = __float2bfloat16(a.z); o.h[3] = __float2bfloat16(a.w);
    o.h[4] = __float2bfloat16(b.x); o.h[5] = __float2bfloat16(b.y);
    o.h[6] = __float2bfloat16(b.z); o.h[7] = __float2bfloat16(b.w);
    *(short8*)(out + base) = o.v;
}

// W [1024(k)][1024(n)] fp32 -> WT [1024(n)][1024(k)] bf16, stacked [3072][1024]
__global__ __launch_bounds__(256) void cvt_w_t(const float* __restrict__ Wq,
                                               const float* __restrict__ Wk,
                                               const float* __restrict__ Wv,
                                               bf16* __restrict__ WT) {
    const float* W = blockIdx.z == 0 ? Wq : (blockIdx.z == 1 ? Wk : Wv);
    bf16* T = WT + (long)blockIdx.z * 1024 * 1024;
    __shared__ float t[32][33];
    int n0 = blockIdx.x * 32, k0 = blockIdx.y * 32;
    int tx = threadIdx.x, ty = threadIdx.y;  // block (32,8)
    #pragma unroll
    for (int i = 0; i < 4; ++i)
        t[ty * 4 + i][tx] = W[(long)(k0 + ty * 4 + i) * 1024 + n0 + tx];
    __syncthreads();
    #pragma unroll
    for (int i = 0; i < 4; ++i)
        T[(long)(n0 + ty * 4 + i) * 1024 + k0 + tx] =
            __float2bfloat16(t[tx][ty * 4 + i]);
}

// ---------------- fused QKV GEMM: 128x128 tile, single-buffer ----------------
// C = x * WT^T; col-block selects Q (bf16), K (bf16), or V (transposed bf16).
// Single-buffer 2-sync K-step (round-1-proven structure; best at low latency
// exposure with high block residency). Swizzled LDS (0 bank conflicts).
__global__ __launch_bounds__(256) void gemm_qkv(
    const bf16* __restrict__ A, const bf16* __restrict__ B,
    bf16* __restrict__ Q, bf16* __restrict__ Kd, bf16* __restrict__ VT) {
    const int tn = blockIdx.x, tm = blockIdx.y;
    const int m0 = tm * 128, n0 = tn * 128;
    __shared__ bf16 As[128 * 32];
    __shared__ bf16 Bs[128 * 32];

    const int tid = threadIdx.x;
    const int wave = tid >> 6, lane = tid & 63;
    const int wr = wave >> 1, wc = wave & 1;
    const int lrow = lane & 15, kg = lane >> 4;

    f32x4 acc[4][4];
    #pragma unroll
    for (int i = 0; i < 4; ++i)
        #pragma unroll
        for (int j = 0; j < 4; ++j) acc[i][j] = (f32x4){0.f, 0.f, 0.f, 0.f};

    const int srow = tid >> 2;
    const int scol = ((((srow >> 1) & 3) ^ (tid & 3)) << 3);  // swizzled src
    const bf16* ap = A + (long)(m0 + srow) * 1024 + scol;
    const bf16* bp = B + (long)(n0 + srow) * 1024 + scol;
    char* asb = (char*)As + tid * 16;
    char* bsb = (char*)Bs + tid * 16;

    for (int k0 = 0; k0 < 1024; k0 += 32) {
        GLD16(ap + k0, asb);
        GLD16(ap + 64L * 1024 + k0, asb + 4096);
        GLD16(bp + k0, bsb);
        GLD16(bp + 64L * 1024 + k0, bsb + 4096);
        __syncthreads();
        short8 af[4], bfr[4];
        #pragma unroll
        for (int mi = 0; mi < 4; ++mi) {
            const int rr = wr * 64 + mi * 16 + lrow;
            af[mi] = *(const short8*)(&As[rr * 32 + ((((rr >> 1) & 3) ^ kg) << 3)]);
        }
        #pragma unroll
        for (int ni = 0; ni < 4; ++ni) {
            const int rr = wc * 64 + ni * 16 + lrow;
            bfr[ni] = *(const short8*)(&Bs[rr * 32 + ((((rr >> 1) & 3) ^ kg) << 3)]);
        }
        #pragma unroll
        for (int mi = 0; mi < 4; ++mi)
            #pragma unroll
            for (int ni = 0; ni < 4; ++ni)
                acc[mi][ni] = __builtin_amdgcn_mfma_f32_16x16x32_bf16(
                    af[mi], bfr[ni], acc[mi][ni], 0, 0, 0);
        __syncthreads();
    }

    // C/D layout: col = lane&15, row = (lane>>4)*4 + j
    const int rb = wr * 64 + (lane >> 4) * 4;
    const int cb = wc * 64 + (lane & 15);
    const int sel = n0 >> 10;  // 0=Q, 1=K, 2=V
    const int nb = n0 & 1023;
    if (sel < 2) {
        bf16* Cb = sel ? Kd : Q;
        #pragma unroll
        for (int mi = 0; mi < 4; ++mi)
            #pragma unroll
            for (int ni = 0; ni < 4; ++ni)
                #pragma unroll
                for (int j = 0; j < 4; ++j)
                    Cb[(long)(m0 + rb + mi * 16 + j) * 1024 + (nb + cb + ni * 16)] =
                        __float2bfloat16(acc[mi][ni][j]);
    } else {
        #pragma unroll
        for (int mi = 0; mi < 4; ++mi)
            #pragma unroll
            for (int ni = 0; ni < 4; ++ni) {
                int gm = m0 + rb + mi * 16;
                int col = nb + cb + ni * 16;
                int b = gm >> 11, mm = gm & 2047;
                union { bf16 h[4]; ushort4 v; } o;
                #pragma unroll
                for (int j = 0; j < 4; ++j)
                    o.h[j] = __float2bfloat16(acc[mi][ni][j]);
                *(ushort4*)(VT + (long)b * 2097152 + (long)col * 2048 + mm) = o.v;
            }
    }
}

// ------------- attention GEMMs: 64x128 tile, single-buffer, high-grid -------
// MODE 0: scores tri-tiles -> E=exp(s/32) bf16 causal + fp32 rowsum atomics
//         grid 4*272: q-tile 64 rows, k-tile 128 cols, tn <= (tm>>1)
// MODE 2: PV heavy-first -> fp32 out / rowsum; Keff=(tm+1)*64
// 4 waves as 2(M)x2(N): wave tile 32x64; acc[2][4].
template <int MODE>
__global__ __launch_bounds__(256) void gemm_att(
    const bf16* __restrict__ A, const bf16* __restrict__ B,
    void* __restrict__ C, float* __restrict__ RS, int lda, int ldb,
    float alpha, long az, long bz) {
    int tm, tn, bi;
    if (MODE == 0) {
        int t = blockIdx.x % 272;
        bi = blockIdx.x / 272;
        // cum(2u)=u*u+u, cum(2u+1)=(u+1)^2 ; count(tm)=(tm>>1)+1
        int m = 2 * (int)sqrtf((float)t);
        if (m > 31) m = 31;
        auto cum = [](int mm) { int u = mm >> 1; return (mm & 1) ? (u + 1) * (u + 1) : u * u + u; };
        while (m < 31 && cum(m + 1) <= t) ++m;
        while (cum(m) > t) --m;
        tm = m; tn = t - cum(m);
    } else {  // PV heavy-first
        tm = 31 - (int)(blockIdx.x >> 5);
        int r = blockIdx.x & 31;
        tn = r & 7; bi = r >> 3;
    }
    const int nk = (MODE == 0) ? 32 : 2 * (tm + 1);  // K-steps of 32
    A += (long)bi * az;
    B += (long)bi * bz;

    const int m0 = tm * 64, n0 = tn * 128;
    __shared__ bf16 As[64 * 32];
    __shared__ bf16 Bs[128 * 32];

    const int tid = threadIdx.x;
    const int wave = tid >> 6, lane = tid & 63;
    const int wr2 = wave >> 1, wc2 = wave & 1;   // 2x2 waves, 32x64 each
    const int lrow = lane & 15, kg = lane >> 4;

    f32x4 acc[2][4];
    #pragma unroll
    for (int i = 0; i < 2; ++i)
        #pragma unroll
        for (int j = 0; j < 4; ++j) acc[i][j] = (f32x4){0.f, 0.f, 0.f, 0.f};

    const int srow = tid >> 2;
    const int scol = ((((srow >> 1) & 3) ^ (tid & 3)) << 3);
    const bf16* ap = A + (long)(m0 + srow) * lda + scol;
    const bf16* bp = B + (long)(n0 + srow) * ldb + scol;
    char* asb = (char*)As + tid * 16;
    char* bsb = (char*)Bs + tid * 16;

    for (int t = 0; t < nk; ++t) {
        const int k0 = t << 5;
        GLD16(ap + k0, asb);
        GLD16(bp + k0, bsb);
        GLD16(bp + 64L * ldb + k0, bsb + 4096);
        __syncthreads();
        short8 af[2], bfr[4];
        #pragma unroll
        for (int mi = 0; mi < 2; ++mi) {
            const int rr = wr2 * 32 + mi * 16 + lrow;
            af[mi] = *(const short8*)(&As[rr * 32 + ((((rr >> 1) & 3) ^ kg) << 3)]);
        }
        #pragma unroll
        for (int ni = 0; ni < 4; ++ni) {
            const int rr = wc2 * 64 + ni * 16 + lrow;
            bfr[ni] = *(const short8*)(&Bs[rr * 32 + ((((rr >> 1) & 3) ^ kg) << 3)]);
        }
        #pragma unroll
        for (int mi = 0; mi < 2; ++mi)
            #pragma unroll
            for (int ni = 0; ni < 4; ++ni)
                acc[mi][ni] = __builtin_amdgcn_mfma_f32_16x16x32_bf16(
                    af[mi], bfr[ni], acc[mi][ni], 0, 0, 0);
        __syncthreads();
    }

    const int rb = wr2 * 32 + (lane >> 4) * 4;
    const int cb = wc2 * 64 + (lane & 15);
    if (MODE == 0) {
        bf16* E = (bf16*)C + (long)bi * 4194304;
        float* rsb = RS + bi * 2048;
        #pragma unroll
        for (int mi = 0; mi < 2; ++mi)
            #pragma unroll
            for (int j = 0; j < 4; ++j) {
                const int gq = m0 + rb + mi * 16 + j;
                float rp = 0.f;
                #pragma unroll
                for (int ni = 0; ni < 4; ++ni) {
                    const int gk = n0 + cb + ni * 16;
                    float e = (gk <= gq) ? __expf(acc[mi][ni][j] * alpha) : 0.f;
                    E[(long)gq * 2048 + gk] = __float2bfloat16(e);
                    rp += e;
                }
                #pragma unroll
                for (int o = 1; o < 16; o <<= 1) rp += __shfl_xor(rp, o);
                if ((lane & 15) == 0) atomicAdd(rsb + gq, rp);
            }
    } else {
        float* Cf = (float*)C + (long)bi * 2097152;
        const float* rsb = RS + bi * 2048;
        #pragma unroll
        for (int mi = 0; mi < 2; ++mi)
            #pragma unroll
            for (int j = 0; j < 4; ++j) {
                const int gq = m0 + rb + mi * 16 + j;
                const float inv = 1.f / rsb[gq];
                #pragma unroll
                for (int ni = 0; ni < 4; ++ni)
                    Cf[(long)gq * 1024 + (n0 + cb + ni * 16)] =
                        acc[mi][ni][j] * inv;
            }
    }
}

// ---------------- launch ----------------
extern "C" void kernel_launch(void* const* d_in, const int* in_sizes, int n_in,
                              void* d_out, int out_size, void* d_ws,
                              size_t ws_size, hipStream_t stream) {
    const float* x = (const float*)d_in[0];
    const float* Wq = (const float*)d_in[1];
    const float* Wk = (const float*)d_in[2];
    const float* Wv = (const float*)d_in[3];
    float* out = (float*)d_out;

    char* ws = (char*)d_ws;
    bf16* xb = (bf16*)ws;                     // 8192x1024 bf16
    bf16* wt = (bf16*)(ws + 16777216);        // 3072x1024 bf16
    bf16* Qb = (bf16*)(ws + 23068672);        // 8192x1024 bf16
    bf16* Kb = (bf16*)(ws + 39845888);        // 8192x1024 bf16
    bf16* VT = (bf16*)(ws + 56623104);        // 4x 1024x2048 bf16
    bf16* E  = (bf16*)(ws + 73400320);        // 4x 2048x2048 bf16
    float* rs = (float*)(ws + 106954752);     // 4x 2048 fp32
    if (ws_size < 106987520) return;

    cvt_x<<<4096, 256, 0, stream>>>(x, xb);
    cvt_w_t<<<dim3(32, 32, 3), dim3(32, 8), 0, stream>>>(Wq, Wk, Wv, wt);
    hipMemsetAsync(rs, 0, 4 * 2048 * sizeof(float), stream);
    // fused QKV: M=8192, N=3072, K=1024 -> 1536 blocks (6/CU)
    gemm_qkv<<<dim3(24, 64), 256, 0, stream>>>(xb, wt, Qb, Kb, VT);
    // E = exp(QK^T/32) causal + rowsums: 4 x 272 = 1088 blocks (4.25/CU)
    gemm_att<0><<<1088, 256, 0, stream>>>(
        Qb, Kb, E, rs, 1024, 1024, 0.03125f, 2097152, 2097152);
    // O = (E V)/rowsum: 1024 blocks (4/CU), heavy-first
    gemm_att<2><<<1024, 256, 0, stream>>>(
        E, VT, out, rs, 2048, 2048, 1.f, 4194304, 2097152);
}